// Round 8
// baseline (1197.072 us; speedup 1.0000x reference)
//
#include <hip/hip_runtime.h>

#define N_USERS 90000
#define N_ITEMS 60000
#define NN      (N_USERS + N_ITEMS)   // 150000
#define D       64
#define KDIM    128
#define NE      1600000
#define EPSF    1e-12f
#define ROWD    96                    // pk row = 96 dwords = 384B
#define TU      ((N_USERS + 63) / 64) // 1407
#define TI      ((N_ITEMS + 63) / 64) // 938
#define NINT    (TU + TI)             // 2345 intent blocks
#define RB      ((NN + 3) / 4)        // 37500 gnn/fused blocks
#define MIDG    (17 * NINT)           // 39865: intent every 17th block

// ---------------- f16 helpers ----------------

typedef __fp16 h2 __attribute__((ext_vector_type(2)));

__device__ inline h2 as_h2(unsigned u) {
    union { unsigned u; h2 h; } v; v.u = u; return v.h;
}
__device__ inline unsigned pkrtz(float a, float b) {
    auto r = __builtin_amdgcn_cvt_pkrtz(a, b);
    union { decltype(r) h; unsigned u; } v; v.h = r; return v.u;
}
__device__ inline float fdot2(h2 a, h2 b, float c) {
#if __has_builtin(__builtin_amdgcn_fdot2)
    return __builtin_amdgcn_fdot2(a, b, c, false);
#else
    return c + (float)a.x * (float)b.x + (float)a.y * (float)b.y;
#endif
}

// ---------------- pre-pass: deg || init || wt (block-specialized) ------------

#define EB   ((NE + 255) / 256)         // 6250
#define IB   ((NN * 16 + 255) / 256)    // 9375
#define PREG (EB + IB + 64)

__global__ void k_pre(const int* __restrict__ h, int* __restrict__ deg,
                      const float* __restrict__ emb, float* __restrict__ xt,
                      float* __restrict__ acc, unsigned* __restrict__ pkA,
                      const float* __restrict__ Wu, const float* __restrict__ Wi,
                      float* __restrict__ WtG) {
    int bid = blockIdx.x;
    if (bid < EB) {
        int e = bid * 256 + threadIdx.x;
        if (e < NE) atomicAdd(&deg[h[e]], 1);
    } else if (bid < EB + IB) {
        int i = (bid - EB) * 256 + threadIdx.x;
        if (i >= NN * 16) return;
        float4 v = ((const float4*)emb)[i];
        ((float4*)xt)[i]  = v;
        ((float4*)acc)[i] = v;
        int row = i >> 4, l = i & 15;
        *(uint2*)&pkA[(size_t)row * ROWD + 64 + 2 * l] =
            make_uint2(pkrtz(v.x, v.y), pkrtz(v.z, v.w));
    } else {
        int i = (bid - EB - IB) * 256 + threadIdx.x;
        if (i >= 2 * D * KDIM) return;
        int m = i >> 13, r = i & 8191;
        int k = r >> 6, d = r & 63;
        const float* W = m ? Wi : Wu;
        WtG[m * 8192 + k * 64 + d] = W[d * KDIM + k];
    }
}

__global__ void k_rowoff(const int* __restrict__ deg, int* __restrict__ counter,
                         int* __restrict__ row_off, float* __restrict__ d_inv) {
    int i = blockIdx.x * blockDim.x + threadIdx.x;
    if (i >= NN) return;
    int d = deg[i];
    row_off[i] = atomicAdd(counter, d);
    d_inv[i]   = (d > 0) ? rsqrtf((float)d) : 0.f;
}

__global__ void k_scatter(const int* __restrict__ h, const int* __restrict__ t,
                          const int* __restrict__ row_off, int* __restrict__ row_cur,
                          const float* __restrict__ d_inv,
                          int2* __restrict__ csr) {
    int e = blockIdx.x * blockDim.x + threadIdx.x;
    if (e >= NE) return;
    int hh = h[e], tt = t[e];
    int slot = row_off[hh] + atomicAdd(&row_cur[hh], 1);
    csr[slot] = make_int2(tt, __float_as_int(d_inv[hh] * d_inv[tt]));
}

// ---------------- k_mid: interleaved  intent || gnn-SPMM ----------------
// bid%17==0 -> intent block (bid/17 in [0,NINT));  else gnn block
__global__ __launch_bounds__(256) void k_mid(const int* __restrict__ row_off,
                                             const int* __restrict__ deg,
                                             const int2* __restrict__ csr,
                                             unsigned* __restrict__ pk,
                                             unsigned* __restrict__ pknx,
                                             const float* __restrict__ xt,
                                             const float* __restrict__ Wu,
                                             const float* __restrict__ Wi,
                                             const float* __restrict__ WtG,
                                             float* __restrict__ base_) {
    __shared__ float xs[64 * 68];      // intent path only
    int tid = threadIdx.x;
    int bid = blockIdx.x;

    if (bid % 17 == 0) {
        // ================= intent path =================
        int ib = bid / 17;
        unsigned* psU = (unsigned*)xs;   // [64][66] packed f16 pairs (union w/ xs)
        const float* W;
        const float* Wt;
        int bse, count, n0;
        if (ib < TU) {
            W = Wu; Wt = WtG;        bse = 0;       count = N_USERS; n0 = ib * 64;
        } else {
            W = Wi; Wt = WtG + 8192; bse = N_USERS; count = N_ITEMS; n0 = (ib - TU) * 64;
        }

        for (int i = tid; i < 64 * 64; i += 256) {
            int nl = i >> 6, d = i & 63;
            int n  = n0 + nl;
            float v = (n < count) ? xt[(size_t)(bse + n) * D + d] : 0.f;
            xs[d * 68 + nl] = v;
        }
        __syncthreads();

        int wv = tid >> 6;
        int la = tid & 63;
        int ag = la >> 4;
        int bg = la & 15;
        int nbase = wv * 16 + ag * 4;

        float acc[4][8];
        #pragma unroll
        for (int i = 0; i < 4; ++i)
            #pragma unroll
            for (int j = 0; j < 8; ++j) acc[i][j] = 0.f;

        #pragma unroll 4
        for (int d = 0; d < 64; ++d) {
            float4 xv = *(const float4*)&xs[d * 68 + nbase];
            float4 wa = *(const float4*)&W[d * KDIM + 4 * bg];
            float4 wb = *(const float4*)&W[d * KDIM + 64 + 4 * bg];
            float xx[4] = {xv.x, xv.y, xv.z, xv.w};
            float wk[8] = {wa.x, wa.y, wa.z, wa.w, wb.x, wb.y, wb.z, wb.w};
            #pragma unroll
            for (int i = 0; i < 4; ++i)
                #pragma unroll
                for (int j = 0; j < 8; ++j)
                    acc[i][j] = fmaf(xx[i], wk[j], acc[i][j]);
        }

        float p[4][8];
        float inv_s[4];
        #pragma unroll
        for (int i = 0; i < 4; ++i) {
            float m = acc[i][0];
            #pragma unroll
            for (int j = 1; j < 8; ++j) m = fmaxf(m, acc[i][j]);
            m = fmaxf(m, __shfl_xor(m, 1));
            m = fmaxf(m, __shfl_xor(m, 2));
            m = fmaxf(m, __shfl_xor(m, 4));
            m = fmaxf(m, __shfl_xor(m, 8));
            float sm = 0.f;
            #pragma unroll
            for (int j = 0; j < 8; ++j) { p[i][j] = __expf(acc[i][j] - m); sm += p[i][j]; }
            sm += __shfl_xor(sm, 1);
            sm += __shfl_xor(sm, 2);
            sm += __shfl_xor(sm, 4);
            sm += __shfl_xor(sm, 8);
            inv_s[i] = 1.f / sm;
        }

        __syncthreads();

        #pragma unroll
        for (int i = 0; i < 4; ++i) {
            float is = inv_s[i];
            #pragma unroll
            for (int j = 0; j < 2; ++j) {
                unsigned u0 = pkrtz(p[i][4 * j + 0] * is, p[i][4 * j + 1] * is);
                unsigned u1 = pkrtz(p[i][4 * j + 2] * is, p[i][4 * j + 3] * is);
                *(uint2*)&psU[(nbase + i) * 66 + 2 * bg + 32 * j] = make_uint2(u0, u1);
            }
        }
        __syncthreads();

        float o[4][4];
        #pragma unroll
        for (int i = 0; i < 4; ++i)
            #pragma unroll
            for (int r = 0; r < 4; ++r) o[i][r] = 0.f;

        int dbase = bg * 4;
        for (int kk = 0; kk < 32; ++kk) {
            uint2 P[4];
            #pragma unroll
            for (int i = 0; i < 4; ++i)
                P[i] = *(const uint2*)&psU[(nbase + i) * 66 + 2 * kk];
            float4 Wv[4];
            #pragma unroll
            for (int c = 0; c < 4; ++c)
                Wv[c] = *(const float4*)&Wt[(4 * kk + c) * 64 + dbase];
            #pragma unroll
            for (int i = 0; i < 4; ++i) {
                h2 pa = as_h2(P[i].x), pb = as_h2(P[i].y);
                float pc[4] = {(float)pa.x, (float)pa.y, (float)pb.x, (float)pb.y};
                #pragma unroll
                for (int c = 0; c < 4; ++c) {
                    o[i][0] = fmaf(pc[c], Wv[c].x, o[i][0]);
                    o[i][1] = fmaf(pc[c], Wv[c].y, o[i][1]);
                    o[i][2] = fmaf(pc[c], Wv[c].z, o[i][2]);
                    o[i][3] = fmaf(pc[c], Wv[c].w, o[i][3]);
                }
            }
        }

        #pragma unroll
        for (int i = 0; i < 4; ++i) {
            int n = n0 + nbase + i;
            float ss = o[i][0]*o[i][0] + o[i][1]*o[i][1] + o[i][2]*o[i][2] + o[i][3]*o[i][3];
            ss += __shfl_xor(ss, 1);
            ss += __shfl_xor(ss, 2);
            ss += __shfl_xor(ss, 4);
            ss += __shfl_xor(ss, 8);
            if (n < count) {
                size_t g = (size_t)(bse + n);
                float invn = 1.0f / fmaxf(sqrtf(ss), EPSF);
                ((float4*)(pknx + g * ROWD))[bg] =
                    make_float4(o[i][0], o[i][1], o[i][2], o[i][3]);
                unsigned* pr = pk + g * ROWD;
                pr[4 * bg + 1] = pkrtz(o[i][0] * invn, o[i][1] * invn);
                pr[4 * bg + 3] = pkrtz(o[i][2] * invn, o[i][3] * invn);
            }
        }
    } else {
        // ================= gnn path =================
        int gb   = bid - bid / 17 - 1;     // dense gnn block index
        int wid  = gb * 4 + (tid >> 6);
        int lane = tid & 63;
        if (wid >= NN) return;
        int grp = lane >> 4, l16 = lane & 15;
        int s = row_off[wid], eend = s + deg[wid];
        float a0 = 0.f, a1 = 0.f, a2 = 0.f, a3 = 0.f;
        int e = s;
        for (; e + 15 < eend; e += 16) {
            int2 cA = csr[e + grp];
            int2 cB = csr[e + 4 + grp];
            int2 cC = csr[e + 8 + grp];
            int2 cD = csr[e + 12 + grp];
            uint2 wA = *(const uint2*)&pk[(size_t)cA.x * ROWD + 64 + 2 * l16];
            uint2 wB = *(const uint2*)&pk[(size_t)cB.x * ROWD + 64 + 2 * l16];
            uint2 wC = *(const uint2*)&pk[(size_t)cC.x * ROWD + 64 + 2 * l16];
            uint2 wD = *(const uint2*)&pk[(size_t)cD.x * ROWD + 64 + 2 * l16];
            float gA = __int_as_float(cA.y), gB = __int_as_float(cB.y);
            float gC = __int_as_float(cC.y), gD = __int_as_float(cD.y);
            h2 xa0 = as_h2(wA.x), xa1 = as_h2(wA.y);
            h2 xb0 = as_h2(wB.x), xb1 = as_h2(wB.y);
            h2 xc0 = as_h2(wC.x), xc1 = as_h2(wC.y);
            h2 xd0 = as_h2(wD.x), xd1 = as_h2(wD.y);
            a0 = fmaf(gA, (float)xa0.x, a0); a1 = fmaf(gA, (float)xa0.y, a1);
            a2 = fmaf(gA, (float)xa1.x, a2); a3 = fmaf(gA, (float)xa1.y, a3);
            a0 = fmaf(gB, (float)xb0.x, a0); a1 = fmaf(gB, (float)xb0.y, a1);
            a2 = fmaf(gB, (float)xb1.x, a2); a3 = fmaf(gB, (float)xb1.y, a3);
            a0 = fmaf(gC, (float)xc0.x, a0); a1 = fmaf(gC, (float)xc0.y, a1);
            a2 = fmaf(gC, (float)xc1.x, a2); a3 = fmaf(gC, (float)xc1.y, a3);
            a0 = fmaf(gD, (float)xd0.x, a0); a1 = fmaf(gD, (float)xd0.y, a1);
            a2 = fmaf(gD, (float)xd1.x, a2); a3 = fmaf(gD, (float)xd1.y, a3);
        }
        for (; e < eend; e += 4) {
            int ee = e + grp;
            bool val = ee < eend;
            int2 c = csr[val ? ee : eend - 1];
            float gv = val ? __int_as_float(c.y) : 0.f;
            uint2 w = *(const uint2*)&pk[(size_t)c.x * ROWD + 64 + 2 * l16];
            h2 x0 = as_h2(w.x), x1 = as_h2(w.y);
            a0 = fmaf(gv, (float)x0.x, a0); a1 = fmaf(gv, (float)x0.y, a1);
            a2 = fmaf(gv, (float)x1.x, a2); a3 = fmaf(gv, (float)x1.y, a3);
        }
        a0 += __shfl_xor(a0, 16); a1 += __shfl_xor(a1, 16);
        a2 += __shfl_xor(a2, 16); a3 += __shfl_xor(a3, 16);
        a0 += __shfl_xor(a0, 32); a1 += __shfl_xor(a1, 32);
        a2 += __shfl_xor(a2, 32); a3 += __shfl_xor(a3, 32);
        float ss = fmaf(a0, a0, fmaf(a1, a1, fmaf(a2, a2, a3 * a3)));
        ss += __shfl_xor(ss, 1); ss += __shfl_xor(ss, 2);
        ss += __shfl_xor(ss, 4); ss += __shfl_xor(ss, 8);
        float inv = 1.f / fmaxf(sqrtf(ss), EPSF);
        if (grp == 0) {
            unsigned* pr = pk + (size_t)wid * ROWD;
            pr[4 * l16]     = pkrtz(a0 * inv, a1 * inv);
            pr[4 * l16 + 2] = pkrtz(a2 * inv, a3 * inv);
            size_t bidx = (size_t)wid * 16 + l16;
            float4 xr = ((const float4*)xt)[bidx];
            float4 bo;
            bo.x = a0 + xr.x; bo.y = a1 + xr.y; bo.z = a2 + xr.z; bo.w = a3 + xr.w;
            ((float4*)base_)[bidx] = bo;
        }
    }
}

// ---------------- k_fused: alphas + gaa/iaa + combine ----------------
// wave = 4 groups x 16 lanes; 16 edges/iter (4 per group in flight)
__global__ __launch_bounds__(256) void k_fused(const int* __restrict__ row_off,
                                               const int* __restrict__ deg,
                                               const int2* __restrict__ csr,
                                               const unsigned* __restrict__ pk,
                                               const float* __restrict__ base_,
                                               float* __restrict__ xt,
                                               unsigned* __restrict__ pknext,
                                               float* __restrict__ acc) {
    int wid  = (blockIdx.x * blockDim.x + threadIdx.x) >> 6;
    int lane = threadIdx.x & 63;
    if (wid >= NN) return;
    int grp = lane >> 4, l16 = lane & 15;

    const unsigned* ph = pk + (size_t)wid * ROWD;
    uint4 hq = *(const uint4*)&ph[4 * l16];
    h2 hg0 = as_h2(hq.x), hi0 = as_h2(hq.y), hg1 = as_h2(hq.z), hi1 = as_h2(hq.w);

    int s = row_off[wid], eend = s + deg[wid];
    float sg = 0.f, si = 0.f;
    float g0 = 0.f, g1 = 0.f, g2 = 0.f, g3 = 0.f;
    float i0 = 0.f, i1 = 0.f, i2 = 0.f, i3 = 0.f;

    int e = s;
    for (; e + 15 < eend; e += 16) {
        int tA = csr[e + grp].x;
        int tB = csr[e + 4 + grp].x;
        int tC = csr[e + 8 + grp].x;
        int tD = csr[e + 12 + grp].x;
        const unsigned* pA = pk + (size_t)tA * ROWD;
        const unsigned* pB = pk + (size_t)tB * ROWD;
        const unsigned* pC = pk + (size_t)tC * ROWD;
        const unsigned* pD = pk + (size_t)tD * ROWD;
        uint4 qA = *(const uint4*)&pA[4 * l16];
        uint4 qB = *(const uint4*)&pB[4 * l16];
        uint4 qC = *(const uint4*)&pC[4 * l16];
        uint4 qD = *(const uint4*)&pD[4 * l16];
        uint2 wA = *(const uint2*)&pA[64 + 2 * l16];
        uint2 wB = *(const uint2*)&pB[64 + 2 * l16];
        uint2 wC = *(const uint2*)&pC[64 + 2 * l16];
        uint2 wD = *(const uint2*)&pD[64 + 2 * l16];
        float pgA = fdot2(hg0, as_h2(qA.x), fdot2(hg1, as_h2(qA.z), 0.f));
        float piA = fdot2(hi0, as_h2(qA.y), fdot2(hi1, as_h2(qA.w), 0.f));
        float pgB = fdot2(hg0, as_h2(qB.x), fdot2(hg1, as_h2(qB.z), 0.f));
        float piB = fdot2(hi0, as_h2(qB.y), fdot2(hi1, as_h2(qB.w), 0.f));
        float pgC = fdot2(hg0, as_h2(qC.x), fdot2(hg1, as_h2(qC.z), 0.f));
        float piC = fdot2(hi0, as_h2(qC.y), fdot2(hi1, as_h2(qC.w), 0.f));
        float pgD = fdot2(hg0, as_h2(qD.x), fdot2(hg1, as_h2(qD.z), 0.f));
        float piD = fdot2(hi0, as_h2(qD.y), fdot2(hi1, as_h2(qD.w), 0.f));
        #pragma unroll
        for (int m = 1; m <= 8; m <<= 1) {
            pgA += __shfl_xor(pgA, m); piA += __shfl_xor(piA, m);
            pgB += __shfl_xor(pgB, m); piB += __shfl_xor(piB, m);
            pgC += __shfl_xor(pgC, m); piC += __shfl_xor(piC, m);
            pgD += __shfl_xor(pgD, m); piD += __shfl_xor(piD, m);
        }
        float agA = fmaf(pgA, 0.5f, 0.5f), aiA = fmaf(piA, 0.5f, 0.5f);
        float agB = fmaf(pgB, 0.5f, 0.5f), aiB = fmaf(piB, 0.5f, 0.5f);
        float agC = fmaf(pgC, 0.5f, 0.5f), aiC = fmaf(piC, 0.5f, 0.5f);
        float agD = fmaf(pgD, 0.5f, 0.5f), aiD = fmaf(piD, 0.5f, 0.5f);
        sg += agA + agB + agC + agD; si += aiA + aiB + aiC + aiD;
        h2 xa0 = as_h2(wA.x), xa1 = as_h2(wA.y);
        h2 xb0 = as_h2(wB.x), xb1 = as_h2(wB.y);
        h2 xc0 = as_h2(wC.x), xc1 = as_h2(wC.y);
        h2 xd0 = as_h2(wD.x), xd1 = as_h2(wD.y);
        g0 = fmaf(agA, (float)xa0.x, g0); g1 = fmaf(agA, (float)xa0.y, g1);
        g2 = fmaf(agA, (float)xa1.x, g2); g3 = fmaf(agA, (float)xa1.y, g3);
        i0 = fmaf(aiA, (float)xa0.x, i0); i1 = fmaf(aiA, (float)xa0.y, i1);
        i2 = fmaf(aiA, (float)xa1.x, i2); i3 = fmaf(aiA, (float)xa1.y, i3);
        g0 = fmaf(agB, (float)xb0.x, g0); g1 = fmaf(agB, (float)xb0.y, g1);
        g2 = fmaf(agB, (float)xb1.x, g2); g3 = fmaf(agB, (float)xb1.y, g3);
        i0 = fmaf(aiB, (float)xb0.x, i0); i1 = fmaf(aiB, (float)xb0.y, i1);
        i2 = fmaf(aiB, (float)xb1.x, i2); i3 = fmaf(aiB, (float)xb1.y, i3);
        g0 = fmaf(agC, (float)xc0.x, g0); g1 = fmaf(agC, (float)xc0.y, g1);
        g2 = fmaf(agC, (float)xc1.x, g2); g3 = fmaf(agC, (float)xc1.y, g3);
        i0 = fmaf(aiC, (float)xc0.x, i0); i1 = fmaf(aiC, (float)xc0.y, i1);
        i2 = fmaf(aiC, (float)xc1.x, i2); i3 = fmaf(aiC, (float)xc1.y, i3);
        g0 = fmaf(agD, (float)xd0.x, g0); g1 = fmaf(agD, (float)xd0.y, g1);
        g2 = fmaf(agD, (float)xd1.x, g2); g3 = fmaf(agD, (float)xd1.y, g3);
        i0 = fmaf(aiD, (float)xd0.x, i0); i1 = fmaf(aiD, (float)xd0.y, i1);
        i2 = fmaf(aiD, (float)xd1.x, i2); i3 = fmaf(aiD, (float)xd1.y, i3);
    }
    for (; e < eend; e += 4) {
        int ee = e + grp;
        bool val = ee < eend;
        int t = csr[val ? ee : eend - 1].x;
        const unsigned* pr = pk + (size_t)t * ROWD;
        uint4 q = *(const uint4*)&pr[4 * l16];
        uint2 w = *(const uint2*)&pr[64 + 2 * l16];
        float pg = fdot2(hg0, as_h2(q.x), fdot2(hg1, as_h2(q.z), 0.f));
        float pi = fdot2(hi0, as_h2(q.y), fdot2(hi1, as_h2(q.w), 0.f));
        #pragma unroll
        for (int m = 1; m <= 8; m <<= 1) {
            pg += __shfl_xor(pg, m); pi += __shfl_xor(pi, m);
        }
        float ag = fmaf(pg, 0.5f, 0.5f), ai = fmaf(pi, 0.5f, 0.5f);
        if (!val) { ag = 0.f; ai = 0.f; }
        sg += ag; si += ai;
        h2 x0 = as_h2(w.x), x1 = as_h2(w.y);
        g0 = fmaf(ag, (float)x0.x, g0); g1 = fmaf(ag, (float)x0.y, g1);
        g2 = fmaf(ag, (float)x1.x, g2); g3 = fmaf(ag, (float)x1.y, g3);
        i0 = fmaf(ai, (float)x0.x, i0); i1 = fmaf(ai, (float)x0.y, i1);
        i2 = fmaf(ai, (float)x1.x, i2); i3 = fmaf(ai, (float)x1.y, i3);
    }

    #pragma unroll
    for (int m = 16; m <= 32; m <<= 1) {
        sg += __shfl_xor(sg, m); si += __shfl_xor(si, m);
        g0 += __shfl_xor(g0, m); g1 += __shfl_xor(g1, m);
        g2 += __shfl_xor(g2, m); g3 += __shfl_xor(g3, m);
        i0 += __shfl_xor(i0, m); i1 += __shfl_xor(i1, m);
        i2 += __shfl_xor(i2, m); i3 += __shfl_xor(i3, m);
    }

    if (grp == 0) {
        float invg = sg > 0.f ? 1.f / sg : 0.f;
        float invi = si > 0.f ? 1.f / si : 0.f;
        size_t bidx = (size_t)wid * 16 + l16;
        float4 b  = ((const float4*)base_)[bidx];
        float4 il = ((const float4*)(pknext + (size_t)wid * ROWD))[l16]; // raw intl
        float o0 = b.x + il.x + invg * g0 + invi * i0;
        float o1 = b.y + il.y + invg * g1 + invi * i1;
        float o2 = b.z + il.z + invg * g2 + invi * i2;
        float o3 = b.w + il.w + invg * g3 + invi * i3;
        float4 ov; ov.x = o0; ov.y = o1; ov.z = o2; ov.w = o3;
        ((float4*)xt)[bidx] = ov;
        *(uint2*)&pknext[(size_t)wid * ROWD + 64 + 2 * l16] =
            make_uint2(pkrtz(o0, o1), pkrtz(o2, o3));
        float4 a = ((float4*)acc)[bidx];
        a.x += o0; a.y += o1; a.z += o2; a.w += o3;
        ((float4*)acc)[bidx] = a;
    }
}

// ---------------- launch ----------------

extern "C" void kernel_launch(void* const* d_in, const int* in_sizes, int n_in,
                              void* d_out, int out_size, void* d_ws, size_t ws_size,
                              hipStream_t stream) {
    const float* emb   = (const float*)d_in[0];
    const float* Wu    = (const float*)d_in[1];
    const float* Wi    = (const float*)d_in[2];
    const int*   all_h = (const int*)d_in[3];
    const int*   all_t = (const int*)d_in[4];
    float*       acc   = (float*)d_out;

    char*  bp  = (char*)d_ws;
    size_t off = 0;
    auto take = [&](size_t bytes) -> char* {
        char* r = bp + off;
        off = (off + bytes + 255) & ~(size_t)255;
        return r;
    };
    int*      deg     = (int*)     take((size_t)NN * 4);
    int*      row_off = (int*)     take((size_t)NN * 4);
    int*      row_cur = (int*)     take((size_t)NN * 4);
    int*      counter = (int*)     take(256);
    float*    d_inv   = (float*)   take((size_t)NN * 4);
    int2*     csr     = (int2*)    take((size_t)NE * 8);
    unsigned* pkA     = (unsigned*)take((size_t)NN * ROWD * 4);
    unsigned* pkB     = (unsigned*)take((size_t)NN * ROWD * 4);
    float*    xt      = (float*)   take((size_t)NN * D * 4);
    float*    base_   = (float*)   take((size_t)NN * D * 4);
    float*    WtG     = (float*)   take((size_t)2 * D * KDIM * 4);
    (void)ws_size; (void)in_sizes; (void)n_in; (void)out_size;

    hipMemsetAsync(deg, 0, (size_t)NN * 4, stream);
    hipMemsetAsync(row_cur, 0, (size_t)NN * 4, stream);
    hipMemsetAsync(counter, 0, 256, stream);

    const int NBK = (NN + 255) / 256;
    k_pre<<<PREG, 256, 0, stream>>>(all_h, deg, emb, xt, acc, pkA, Wu, Wi, WtG);
    k_rowoff<<<NBK, 256, 0, stream>>>(deg, counter, row_off, d_inv);
    k_scatter<<<EB, 256, 0, stream>>>(all_h, all_t, row_off, row_cur, d_inv, csr);

    unsigned* cur = pkA;
    unsigned* nxt = pkB;
    for (int l = 0; l < 3; ++l) {
        k_mid<<<MIDG, 256, 0, stream>>>(row_off, deg, csr, cur, nxt,
                                        xt, Wu, Wi, WtG, base_);
        k_fused<<<RB, 256, 0, stream>>>(row_off, deg, csr, cur, base_, xt, nxt, acc);
        unsigned* tmp = cur; cur = nxt; nxt = tmp;
    }
}

// Round 9
// 936.499 us; speedup vs baseline: 1.2782x; 1.2782x over previous
//
#include <hip/hip_runtime.h>

#define N_USERS 90000
#define N_ITEMS 60000
#define NN      (N_USERS + N_ITEMS)   // 150000
#define D       64
#define KDIM    128
#define NE      1600000
#define EPSF    1e-12f
#define ROWD    64                    // pk row = 64 dwords = 256B
#define TU      ((N_USERS + 63) / 64) // 1407
#define TI      ((N_ITEMS + 63) / 64) // 938
#define NINT    (TU + TI)             // 2345 intent blocks
#define RB      ((NN + 3) / 4)        // 37500 gnn/fused blocks

// ---------------- f16 / fp8 helpers ----------------

typedef __fp16 h2 __attribute__((ext_vector_type(2)));
typedef float  f2 __attribute__((ext_vector_type(2)));

__device__ inline h2 as_h2(unsigned u) {
    union { unsigned u; h2 h; } v; v.u = u; return v.h;
}
__device__ inline unsigned pkrtz(float a, float b) {
    auto r = __builtin_amdgcn_cvt_pkrtz(a, b);
    union { decltype(r) h; unsigned u; } v; v.h = r; return v.u;
}
__device__ inline f2 dec8lo(unsigned u) {
    return __builtin_amdgcn_cvt_pk_f32_fp8((int)u, false);
}
__device__ inline f2 dec8hi(unsigned u) {
    return __builtin_amdgcn_cvt_pk_f32_fp8((int)u, true);
}
__device__ inline unsigned enc8(float a, float b, float c, float d) {
    int u = __builtin_amdgcn_cvt_pk_fp8_f32(a, b, 0, false);
    u = __builtin_amdgcn_cvt_pk_fp8_f32(c, d, u, true);
    return (unsigned)u;
}

// ---------------- pre-pass: deg || init || wt (block-specialized) ------------

#define EB   ((NE + 255) / 256)         // 6250
#define IB   ((NN * 16 + 255) / 256)    // 9375
#define PREG (EB + IB + 64)

__global__ void k_pre(const int* __restrict__ h, int* __restrict__ deg,
                      const float* __restrict__ emb,
                      float* __restrict__ acc, unsigned* __restrict__ pkA,
                      const float* __restrict__ Wu, const float* __restrict__ Wi,
                      float* __restrict__ WtG) {
    int bid = blockIdx.x;
    if (bid < EB) {
        int e = bid * 256 + threadIdx.x;
        if (e < NE) atomicAdd(&deg[h[e]], 1);
    } else if (bid < EB + IB) {
        int i = (bid - EB) * 256 + threadIdx.x;
        if (i >= NN * 16) return;
        float4 v = ((const float4*)emb)[i];
        ((float4*)acc)[i] = v;
        int row = i >> 4, l = i & 15;
        *(uint2*)&pkA[(size_t)row * ROWD + 32 + 2 * l] =
            make_uint2(pkrtz(v.x, v.y), pkrtz(v.z, v.w));
    } else {
        int i = (bid - EB - IB) * 256 + threadIdx.x;
        if (i >= 2 * D * KDIM) return;
        int m = i >> 13, r = i & 8191;
        int k = r >> 6, d = r & 63;
        const float* W = m ? Wi : Wu;
        WtG[m * 8192 + k * 64 + d] = W[d * KDIM + k];
    }
}

__global__ void k_rowoff(const int* __restrict__ deg, int* __restrict__ counter,
                         int* __restrict__ row_off, float* __restrict__ d_inv) {
    int i = blockIdx.x * blockDim.x + threadIdx.x;
    if (i >= NN) return;
    int d = deg[i];
    row_off[i] = atomicAdd(counter, d);
    d_inv[i]   = (d > 0) ? rsqrtf((float)d) : 0.f;
}

__global__ void k_scatter(const int* __restrict__ h, const int* __restrict__ t,
                          const int* __restrict__ row_off, int* __restrict__ row_cur,
                          const float* __restrict__ d_inv,
                          int2* __restrict__ csr) {
    int e = blockIdx.x * blockDim.x + threadIdx.x;
    if (e >= NE) return;
    int hh = h[e], tt = t[e];
    int slot = row_off[hh] + atomicAdd(&row_cur[hh], 1);
    csr[slot] = make_int2(tt, __float_as_int(d_inv[hh] * d_inv[tt]));
}

// ---------------- k_mid: intent blocks then gnn blocks ----------------
// pk row (64 dwords): [2i]=ghat fp8x4 dims 4i..4i+3, [2i+1]=ihat fp8x4,
//                     [32+2i,33+2i]=x f16 dims 4i..4i+3
__global__ __launch_bounds__(256) void k_mid(const int* __restrict__ row_off,
                                             const int* __restrict__ deg,
                                             const int2* __restrict__ csr,
                                             unsigned* __restrict__ pk,
                                             unsigned* __restrict__ intl_h,
                                             const float* __restrict__ Wu,
                                             const float* __restrict__ Wi,
                                             const float* __restrict__ WtG,
                                             float* __restrict__ base_) {
    __shared__ float xs[64 * 68];      // intent path only
    int tid = threadIdx.x;
    int bid = blockIdx.x;

    if (bid < NINT) {
        // ================= intent path =================
        unsigned* psU = (unsigned*)xs;   // [64][66] packed f16 pairs (union w/ xs)
        const float* W;
        const float* Wt;
        int bse, count, n0;
        if (bid < TU) {
            W = Wu; Wt = WtG;        bse = 0;       count = N_USERS; n0 = bid * 64;
        } else {
            W = Wi; Wt = WtG + 8192; bse = N_USERS; count = N_ITEMS; n0 = (bid - TU) * 64;
        }

        // stage x tile (f16 from pk) transposed into xs
        for (int i = tid; i < 64 * 32; i += 256) {
            int nl = i >> 5, dw = i & 31;
            int n  = n0 + nl;
            unsigned u = (n < count) ? pk[(size_t)(bse + n) * ROWD + 32 + dw] : 0u;
            h2 xv = as_h2(u);
            xs[(2 * dw) * 68 + nl]     = (float)xv.x;
            xs[(2 * dw + 1) * 68 + nl] = (float)xv.y;
        }
        __syncthreads();

        int wv = tid >> 6;
        int la = tid & 63;
        int ag = la >> 4;
        int bg = la & 15;
        int nbase = wv * 16 + ag * 4;

        float acc[4][8];
        #pragma unroll
        for (int i = 0; i < 4; ++i)
            #pragma unroll
            for (int j = 0; j < 8; ++j) acc[i][j] = 0.f;

        #pragma unroll 4
        for (int d = 0; d < 64; ++d) {
            float4 xv = *(const float4*)&xs[d * 68 + nbase];
            float4 wa = *(const float4*)&W[d * KDIM + 4 * bg];
            float4 wb = *(const float4*)&W[d * KDIM + 64 + 4 * bg];
            float xx[4] = {xv.x, xv.y, xv.z, xv.w};
            float wk[8] = {wa.x, wa.y, wa.z, wa.w, wb.x, wb.y, wb.z, wb.w};
            #pragma unroll
            for (int i = 0; i < 4; ++i)
                #pragma unroll
                for (int j = 0; j < 8; ++j)
                    acc[i][j] = fmaf(xx[i], wk[j], acc[i][j]);
        }

        float p[4][8];
        float inv_s[4];
        #pragma unroll
        for (int i = 0; i < 4; ++i) {
            float m = acc[i][0];
            #pragma unroll
            for (int j = 1; j < 8; ++j) m = fmaxf(m, acc[i][j]);
            m = fmaxf(m, __shfl_xor(m, 1));
            m = fmaxf(m, __shfl_xor(m, 2));
            m = fmaxf(m, __shfl_xor(m, 4));
            m = fmaxf(m, __shfl_xor(m, 8));
            float sm = 0.f;
            #pragma unroll
            for (int j = 0; j < 8; ++j) { p[i][j] = __expf(acc[i][j] - m); sm += p[i][j]; }
            sm += __shfl_xor(sm, 1);
            sm += __shfl_xor(sm, 2);
            sm += __shfl_xor(sm, 4);
            sm += __shfl_xor(sm, 8);
            inv_s[i] = 1.f / sm;
        }

        __syncthreads();

        #pragma unroll
        for (int i = 0; i < 4; ++i) {
            float is = inv_s[i];
            #pragma unroll
            for (int j = 0; j < 2; ++j) {
                unsigned u0 = pkrtz(p[i][4 * j + 0] * is, p[i][4 * j + 1] * is);
                unsigned u1 = pkrtz(p[i][4 * j + 2] * is, p[i][4 * j + 3] * is);
                *(uint2*)&psU[(nbase + i) * 66 + 2 * bg + 32 * j] = make_uint2(u0, u1);
            }
        }
        __syncthreads();

        float o[4][4];
        #pragma unroll
        for (int i = 0; i < 4; ++i)
            #pragma unroll
            for (int r = 0; r < 4; ++r) o[i][r] = 0.f;

        int dbase = bg * 4;
        for (int kk = 0; kk < 32; ++kk) {
            uint2 P[4];
            #pragma unroll
            for (int i = 0; i < 4; ++i)
                P[i] = *(const uint2*)&psU[(nbase + i) * 66 + 2 * kk];
            float4 Wv[4];
            #pragma unroll
            for (int c = 0; c < 4; ++c)
                Wv[c] = *(const float4*)&Wt[(4 * kk + c) * 64 + dbase];
            #pragma unroll
            for (int i = 0; i < 4; ++i) {
                h2 pa = as_h2(P[i].x), pb = as_h2(P[i].y);
                float pc[4] = {(float)pa.x, (float)pa.y, (float)pb.x, (float)pb.y};
                #pragma unroll
                for (int c = 0; c < 4; ++c) {
                    o[i][0] = fmaf(pc[c], Wv[c].x, o[i][0]);
                    o[i][1] = fmaf(pc[c], Wv[c].y, o[i][1]);
                    o[i][2] = fmaf(pc[c], Wv[c].z, o[i][2]);
                    o[i][3] = fmaf(pc[c], Wv[c].w, o[i][3]);
                }
            }
        }

        #pragma unroll
        for (int i = 0; i < 4; ++i) {
            int n = n0 + nbase + i;
            float ss = o[i][0]*o[i][0] + o[i][1]*o[i][1] + o[i][2]*o[i][2] + o[i][3]*o[i][3];
            ss += __shfl_xor(ss, 1);
            ss += __shfl_xor(ss, 2);
            ss += __shfl_xor(ss, 4);
            ss += __shfl_xor(ss, 8);
            if (n < count) {
                size_t g = (size_t)(bse + n);
                float invn = 1.0f / fmaxf(sqrtf(ss), EPSF);
                // raw intl (f16) -> intl_h
                *(uint2*)&intl_h[g * 32 + 2 * bg] =
                    make_uint2(pkrtz(o[i][0], o[i][1]), pkrtz(o[i][2], o[i][3]));
                // normalized ihat (fp8x4) -> odd dword
                pk[g * ROWD + 2 * bg + 1] =
                    enc8(o[i][0] * invn, o[i][1] * invn, o[i][2] * invn, o[i][3] * invn);
            }
        }
    } else {
        // ================= gnn path =================
        int wid  = (bid - NINT) * 4 + (tid >> 6);
        int lane = tid & 63;
        if (wid >= NN) return;
        int grp = lane >> 4, l16 = lane & 15;
        int s = row_off[wid], eend = s + deg[wid];
        float a0 = 0.f, a1 = 0.f, a2 = 0.f, a3 = 0.f;
        int e = s;
        for (; e + 7 < eend; e += 8) {
            int2 cA = csr[e + grp];
            int2 cB = csr[e + 4 + grp];
            uint2 wA = *(const uint2*)&pk[(size_t)cA.x * ROWD + 32 + 2 * l16];
            uint2 wB = *(const uint2*)&pk[(size_t)cB.x * ROWD + 32 + 2 * l16];
            float gA = __int_as_float(cA.y), gB = __int_as_float(cB.y);
            h2 xa0 = as_h2(wA.x), xa1 = as_h2(wA.y);
            h2 xb0 = as_h2(wB.x), xb1 = as_h2(wB.y);
            a0 = fmaf(gA, (float)xa0.x, a0); a1 = fmaf(gA, (float)xa0.y, a1);
            a2 = fmaf(gA, (float)xa1.x, a2); a3 = fmaf(gA, (float)xa1.y, a3);
            a0 = fmaf(gB, (float)xb0.x, a0); a1 = fmaf(gB, (float)xb0.y, a1);
            a2 = fmaf(gB, (float)xb1.x, a2); a3 = fmaf(gB, (float)xb1.y, a3);
        }
        for (; e < eend; e += 4) {
            int ee = e + grp;
            bool val = ee < eend;
            int2 c = csr[val ? ee : eend - 1];
            float gv = val ? __int_as_float(c.y) : 0.f;
            uint2 w = *(const uint2*)&pk[(size_t)c.x * ROWD + 32 + 2 * l16];
            h2 x0 = as_h2(w.x), x1 = as_h2(w.y);
            a0 = fmaf(gv, (float)x0.x, a0); a1 = fmaf(gv, (float)x0.y, a1);
            a2 = fmaf(gv, (float)x1.x, a2); a3 = fmaf(gv, (float)x1.y, a3);
        }
        a0 += __shfl_xor(a0, 16); a1 += __shfl_xor(a1, 16);
        a2 += __shfl_xor(a2, 16); a3 += __shfl_xor(a3, 16);
        a0 += __shfl_xor(a0, 32); a1 += __shfl_xor(a1, 32);
        a2 += __shfl_xor(a2, 32); a3 += __shfl_xor(a3, 32);
        float ss = fmaf(a0, a0, fmaf(a1, a1, fmaf(a2, a2, a3 * a3)));
        ss += __shfl_xor(ss, 1); ss += __shfl_xor(ss, 2);
        ss += __shfl_xor(ss, 4); ss += __shfl_xor(ss, 8);
        float inv = 1.f / fmaxf(sqrtf(ss), EPSF);
        if (grp == 0) {
            // ghat fp8x4 -> even dword
            pk[(size_t)wid * ROWD + 2 * l16] =
                enc8(a0 * inv, a1 * inv, a2 * inv, a3 * inv);
            // base_ = gnn + x (own x f16 from pk)
            uint2 xw = *(const uint2*)&pk[(size_t)wid * ROWD + 32 + 2 * l16];
            h2 x0 = as_h2(xw.x), x1 = as_h2(xw.y);
            float4 bo;
            bo.x = a0 + (float)x0.x; bo.y = a1 + (float)x0.y;
            bo.z = a2 + (float)x1.x; bo.w = a3 + (float)x1.y;
            ((float4*)base_)[(size_t)wid * 16 + l16] = bo;
        }
    }
}

// ---------------- k_fused: alphas + gaa/iaa + combine ----------------
// wave = 4 groups x 16 lanes; group g handles edge e+g; lane l16 owns dims 4*l16..+3
__global__ __launch_bounds__(256) void k_fused(const int* __restrict__ row_off,
                                               const int* __restrict__ deg,
                                               const int2* __restrict__ csr,
                                               const unsigned* __restrict__ pk,
                                               const unsigned* __restrict__ intl_h,
                                               const float* __restrict__ base_,
                                               unsigned* __restrict__ pknext,
                                               float* __restrict__ acc) {
    int wid  = (blockIdx.x * blockDim.x + threadIdx.x) >> 6;
    int lane = threadIdx.x & 63;
    if (wid >= NN) return;
    int grp = lane >> 4, l16 = lane & 15;

    const unsigned* ph = pk + (size_t)wid * ROWD;
    uint2 hq = *(const uint2*)&ph[2 * l16];
    f2 hgl = dec8lo(hq.x), hgh = dec8hi(hq.x);
    f2 hil = dec8lo(hq.y), hih = dec8hi(hq.y);

    int s = row_off[wid], eend = s + deg[wid];
    float sg = 0.f, si = 0.f;
    float g0 = 0.f, g1 = 0.f, g2 = 0.f, g3 = 0.f;
    float i0 = 0.f, i1 = 0.f, i2 = 0.f, i3 = 0.f;

    int e = s;
    for (; e + 7 < eend; e += 8) {
        int tA = csr[e + grp].x;
        int tB = csr[e + 4 + grp].x;
        const unsigned* pA = pk + (size_t)tA * ROWD;
        const unsigned* pB = pk + (size_t)tB * ROWD;
        uint2 qA = *(const uint2*)&pA[2 * l16];
        uint2 wA = *(const uint2*)&pA[32 + 2 * l16];
        uint2 qB = *(const uint2*)&pB[2 * l16];
        uint2 wB = *(const uint2*)&pB[32 + 2 * l16];
        f2 gA01 = dec8lo(qA.x), gA23 = dec8hi(qA.x);
        f2 iA01 = dec8lo(qA.y), iA23 = dec8hi(qA.y);
        f2 gB01 = dec8lo(qB.x), gB23 = dec8hi(qB.x);
        f2 iB01 = dec8lo(qB.y), iB23 = dec8hi(qB.y);
        float pgA = fmaf(hgl.x, gA01.x, fmaf(hgl.y, gA01.y,
                    fmaf(hgh.x, gA23.x, hgh.y * gA23.y)));
        float piA = fmaf(hil.x, iA01.x, fmaf(hil.y, iA01.y,
                    fmaf(hih.x, iA23.x, hih.y * iA23.y)));
        float pgB = fmaf(hgl.x, gB01.x, fmaf(hgl.y, gB01.y,
                    fmaf(hgh.x, gB23.x, hgh.y * gB23.y)));
        float piB = fmaf(hil.x, iB01.x, fmaf(hil.y, iB01.y,
                    fmaf(hih.x, iB23.x, hih.y * iB23.y)));
        #pragma unroll
        for (int m = 1; m <= 8; m <<= 1) {
            pgA += __shfl_xor(pgA, m); piA += __shfl_xor(piA, m);
            pgB += __shfl_xor(pgB, m); piB += __shfl_xor(piB, m);
        }
        float agA = fmaf(pgA, 0.5f, 0.5f), aiA = fmaf(piA, 0.5f, 0.5f);
        float agB = fmaf(pgB, 0.5f, 0.5f), aiB = fmaf(piB, 0.5f, 0.5f);
        sg += agA + agB; si += aiA + aiB;
        h2 xa0 = as_h2(wA.x), xa1 = as_h2(wA.y);
        h2 xb0 = as_h2(wB.x), xb1 = as_h2(wB.y);
        g0 = fmaf(agA, (float)xa0.x, g0); g1 = fmaf(agA, (float)xa0.y, g1);
        g2 = fmaf(agA, (float)xa1.x, g2); g3 = fmaf(agA, (float)xa1.y, g3);
        i0 = fmaf(aiA, (float)xa0.x, i0); i1 = fmaf(aiA, (float)xa0.y, i1);
        i2 = fmaf(aiA, (float)xa1.x, i2); i3 = fmaf(aiA, (float)xa1.y, i3);
        g0 = fmaf(agB, (float)xb0.x, g0); g1 = fmaf(agB, (float)xb0.y, g1);
        g2 = fmaf(agB, (float)xb1.x, g2); g3 = fmaf(agB, (float)xb1.y, g3);
        i0 = fmaf(aiB, (float)xb0.x, i0); i1 = fmaf(aiB, (float)xb0.y, i1);
        i2 = fmaf(aiB, (float)xb1.x, i2); i3 = fmaf(aiB, (float)xb1.y, i3);
    }
    for (; e < eend; e += 4) {
        int ee = e + grp;
        bool val = ee < eend;
        int t = csr[val ? ee : eend - 1].x;
        const unsigned* pr = pk + (size_t)t * ROWD;
        uint2 q = *(const uint2*)&pr[2 * l16];
        uint2 w = *(const uint2*)&pr[32 + 2 * l16];
        f2 tg01 = dec8lo(q.x), tg23 = dec8hi(q.x);
        f2 ti01 = dec8lo(q.y), ti23 = dec8hi(q.y);
        float pg = fmaf(hgl.x, tg01.x, fmaf(hgl.y, tg01.y,
                   fmaf(hgh.x, tg23.x, hgh.y * tg23.y)));
        float pi = fmaf(hil.x, ti01.x, fmaf(hil.y, ti01.y,
                   fmaf(hih.x, ti23.x, hih.y * ti23.y)));
        #pragma unroll
        for (int m = 1; m <= 8; m <<= 1) {
            pg += __shfl_xor(pg, m); pi += __shfl_xor(pi, m);
        }
        float ag = fmaf(pg, 0.5f, 0.5f), ai = fmaf(pi, 0.5f, 0.5f);
        if (!val) { ag = 0.f; ai = 0.f; }
        sg += ag; si += ai;
        h2 x0 = as_h2(w.x), x1 = as_h2(w.y);
        g0 = fmaf(ag, (float)x0.x, g0); g1 = fmaf(ag, (float)x0.y, g1);
        g2 = fmaf(ag, (float)x1.x, g2); g3 = fmaf(ag, (float)x1.y, g3);
        i0 = fmaf(ai, (float)x0.x, i0); i1 = fmaf(ai, (float)x0.y, i1);
        i2 = fmaf(ai, (float)x1.x, i2); i3 = fmaf(ai, (float)x1.y, i3);
    }

    #pragma unroll
    for (int m = 16; m <= 32; m <<= 1) {
        sg += __shfl_xor(sg, m); si += __shfl_xor(si, m);
        g0 += __shfl_xor(g0, m); g1 += __shfl_xor(g1, m);
        g2 += __shfl_xor(g2, m); g3 += __shfl_xor(g3, m);
        i0 += __shfl_xor(i0, m); i1 += __shfl_xor(i1, m);
        i2 += __shfl_xor(i2, m); i3 += __shfl_xor(i3, m);
    }

    if (grp == 0) {
        float invg = sg > 0.f ? 1.f / sg : 0.f;
        float invi = si > 0.f ? 1.f / si : 0.f;
        size_t bidx = (size_t)wid * 16 + l16;
        float4 b = ((const float4*)base_)[bidx];
        uint2 iw = *(const uint2*)&intl_h[(size_t)wid * 32 + 2 * l16];
        h2 il0 = as_h2(iw.x), il1 = as_h2(iw.y);
        float o0 = b.x + (float)il0.x + invg * g0 + invi * i0;
        float o1 = b.y + (float)il0.y + invg * g1 + invi * i1;
        float o2 = b.z + (float)il1.x + invg * g2 + invi * i2;
        float o3 = b.w + (float)il1.y + invg * g3 + invi * i3;
        *(uint2*)&pknext[(size_t)wid * ROWD + 32 + 2 * l16] =
            make_uint2(pkrtz(o0, o1), pkrtz(o2, o3));
        float4 a = ((float4*)acc)[bidx];
        a.x += o0; a.y += o1; a.z += o2; a.w += o3;
        ((float4*)acc)[bidx] = a;
    }
}

// ---------------- launch ----------------

extern "C" void kernel_launch(void* const* d_in, const int* in_sizes, int n_in,
                              void* d_out, int out_size, void* d_ws, size_t ws_size,
                              hipStream_t stream) {
    const float* emb   = (const float*)d_in[0];
    const float* Wu    = (const float*)d_in[1];
    const float* Wi    = (const float*)d_in[2];
    const int*   all_h = (const int*)d_in[3];
    const int*   all_t = (const int*)d_in[4];
    float*       acc   = (float*)d_out;

    char*  bp  = (char*)d_ws;
    size_t off = 0;
    auto take = [&](size_t bytes) -> char* {
        char* r = bp + off;
        off = (off + bytes + 255) & ~(size_t)255;
        return r;
    };
    int*      deg     = (int*)     take((size_t)NN * 4);
    int*      row_off = (int*)     take((size_t)NN * 4);
    int*      row_cur = (int*)     take((size_t)NN * 4);
    int*      counter = (int*)     take(256);
    float*    d_inv   = (float*)   take((size_t)NN * 4);
    int2*     csr     = (int2*)    take((size_t)NE * 8);
    unsigned* pkA     = (unsigned*)take((size_t)NN * ROWD * 4);
    unsigned* pkB     = (unsigned*)take((size_t)NN * ROWD * 4);
    unsigned* intl_h  = (unsigned*)take((size_t)NN * 32 * 4);
    float*    base_   = (float*)   take((size_t)NN * D * 4);
    float*    WtG     = (float*)   take((size_t)2 * D * KDIM * 4);
    (void)ws_size; (void)in_sizes; (void)n_in; (void)out_size;

    hipMemsetAsync(deg, 0, (size_t)NN * 4, stream);
    hipMemsetAsync(row_cur, 0, (size_t)NN * 4, stream);
    hipMemsetAsync(counter, 0, 256, stream);

    const int NBK = (NN + 255) / 256;
    k_pre<<<PREG, 256, 0, stream>>>(all_h, deg, emb, acc, pkA, Wu, Wi, WtG);
    k_rowoff<<<NBK, 256, 0, stream>>>(deg, counter, row_off, d_inv);
    k_scatter<<<EB, 256, 0, stream>>>(all_h, all_t, row_off, row_cur, d_inv, csr);

    unsigned* cur = pkA;
    unsigned* nxt = pkB;
    for (int l = 0; l < 3; ++l) {
        k_mid<<<NINT + RB, 256, 0, stream>>>(row_off, deg, csr, cur, intl_h,
                                             Wu, Wi, WtG, base_);
        k_fused<<<RB, 256, 0, stream>>>(row_off, deg, csr, cur, intl_h,
                                        base_, nxt, acc);
        unsigned* tmp = cur; cur = nxt; nxt = tmp;
    }
}